// Round 15
// baseline (366.576 us; speedup 1.0000x reference)
//
#include <hip/hip_runtime.h>
#include <hip/hip_bf16.h>
#include <hip/hip_fp16.h>
#include <math.h>

// ---------------------------------------------------------------------------
// GAT (3-layer, DGL-style) on MI355X.
// CSR build via bucketed counting sort (u32-packed, no global atomics).
// Per layer:
//   gemm_mfma: bf16 split (hi+lo) MFMA GEMM (fp32 accuracy at matrix rate).
//   gat_aggregate: fused attention-weight + gather-accumulate, 4 nodes/wave,
//                  depth-2 pipelined 8-edge batches (32 loads in flight).
// ft16/hbuf16 fp16 intermediates (L0/L1); layer-2 ft and final out fp32.
// ---------------------------------------------------------------------------

constexpr int BSH = 9;            // 512 nodes per bucket
constexpr int EPB = 4096;         // edges per sort block

typedef __attribute__((ext_vector_type(8))) short bf16x8;
typedef __attribute__((ext_vector_type(4))) float f32x4;

__device__ __forceinline__ ushort bf16_rne(float f) {
    unsigned u = __float_as_uint(f);
    u += 0x7FFF + ((u >> 16) & 1);
    return (ushort)(u >> 16);
}
__device__ __forceinline__ float bf16_tof(ushort h) {
    return __uint_as_float(((unsigned)h) << 16);
}

// ---------------- CSR build ----------------

__global__ __launch_bounds__(256) void ehist(const int* __restrict__ dst,
                                             int* __restrict__ cmat,
                                             int E, int nebs) {
    __shared__ int lh[256];
    const int t = threadIdx.x;
    lh[t] = 0;
    __syncthreads();
    const int base = blockIdx.x * EPB;
    const int cntE = min(EPB, E - base);
    for (int i = t; i < cntE; i += 256) atomicAdd(&lh[dst[base + i] >> BSH], 1);
    __syncthreads();
    cmat[t * nebs + blockIdx.x] = lh[t];  // bucket-major
}

__global__ __launch_bounds__(512) void bscan(int* __restrict__ cmat,
                                             int* __restrict__ rowtot, int nebs) {
    __shared__ int sh[512];
    const int b = blockIdx.x, t = threadIdx.x;
    int v = (t < nebs) ? cmat[b * nebs + t] : 0;
    sh[t] = v;
    __syncthreads();
    for (int off = 1; off < 512; off <<= 1) {
        int u = (t >= off) ? sh[t - off] : 0;
        __syncthreads();
        sh[t] += u;
        __syncthreads();
    }
    if (t < nebs) cmat[b * nebs + t] = sh[t] - v;
    if (t == 511) rowtot[b] = sh[511];
}

__global__ __launch_bounds__(256) void bbase_scan(const int* __restrict__ rowtot,
                                                  int* __restrict__ bbase, int nbuck) {
    __shared__ int sh[256];
    const int t = threadIdx.x;
    int v = (t < nbuck) ? rowtot[t] : 0;
    sh[t] = v;
    __syncthreads();
    for (int off = 1; off < 256; off <<= 1) {
        int u = (t >= off) ? sh[t - off] : 0;
        __syncthreads();
        sh[t] += u;
        __syncthreads();
    }
    bbase[t] = sh[t] - v;  // exclusive
}

__global__ __launch_bounds__(256) void escatter(
    const int* __restrict__ src, const int* __restrict__ dst,
    const int* __restrict__ cmat, const int* __restrict__ bbase,
    unsigned* __restrict__ ebuf, int E, int nebs) {
    __shared__ unsigned sbuf[EPB];        // 16 KB
    __shared__ unsigned char sbk[EPB];    // 4 KB
    __shared__ int lh[256], lstart[256], lcur[256], sh[256];
    const int t = threadIdx.x;
    const int base = blockIdx.x * EPB;
    const int cntE = min(EPB, E - base);

    lh[t] = 0;
    __syncthreads();
    for (int i = t; i < cntE; i += 256) atomicAdd(&lh[dst[base + i] >> BSH], 1);
    __syncthreads();
    {
        int v = lh[t];
        sh[t] = v;
        __syncthreads();
        for (int off = 1; off < 256; off <<= 1) {
            int u = (t >= off) ? sh[t - off] : 0;
            __syncthreads();
            sh[t] += u;
            __syncthreads();
        }
        lstart[t] = sh[t] - v;
        lcur[t] = sh[t] - v;
    }
    __syncthreads();
    for (int i = t; i < cntE; i += 256) {
        int d = dst[base + i], s = src[base + i];
        int bk = d >> BSH;
        int r = atomicAdd(&lcur[bk], 1);
        sbuf[r] = ((unsigned)(d & 511) << 17) | (unsigned)s;
        sbk[r] = (unsigned char)bk;
    }
    __syncthreads();
    for (int j = t; j < cntE; j += 256) {
        int bk = sbk[j];
        int gpos = bbase[bk] + cmat[bk * nebs + blockIdx.x] + (j - lstart[bk]);
        ebuf[gpos] = sbuf[j];
    }
}

__global__ __launch_bounds__(512) void bucket_fill(
    const unsigned* __restrict__ ebuf, const int* __restrict__ bbase,
    int* __restrict__ rowptr, int* __restrict__ colx, int N, int E, int nbuck) {
    __shared__ int cnt[512], nxtl[512], sh[512];
    const int b = blockIdx.x, t = threadIdx.x;
    const int nodebase = b << BSH;
    const int nn = min(512, N - nodebase);
    const int estart = bbase[b];
    const int eend = (b + 1 < 256) ? bbase[b + 1] : E;

    cnt[t] = 0;
    __syncthreads();
    for (int i = estart + t; i < eend; i += 512)
        atomicAdd(&cnt[ebuf[i] >> 17], 1);
    __syncthreads();
    int v = cnt[t];
    sh[t] = v;
    __syncthreads();
    for (int off = 1; off < 512; off <<= 1) {
        int u = (t >= off) ? sh[t - off] : 0;
        __syncthreads();
        sh[t] += u;
        __syncthreads();
    }
    if (t < nn) rowptr[nodebase + t + 1] = estart + sh[t];
    if (b == 0 && t == 0) rowptr[0] = 0;
    nxtl[t] = estart + sh[t] - v;
    __syncthreads();
    for (int i = estart + t; i < eend; i += 512) {
        unsigned v2 = ebuf[i];
        int dl = v2 >> 17;
        int pos = atomicAdd(&nxtl[dl], 1);
        colx[pos] = (int)(v2 & 0x1FFFFu);
    }
}

// ---------------- W prep (all 3 weights, one launch) ----------------
// Layout: [kstep:K/32][tile:FOUT/16][half:2][lane:64][i:8] ushort.

__global__ __launch_bounds__(256) void wprep_all(
    const float* __restrict__ W0, const float* __restrict__ W1,
    const float* __restrict__ W2, ushort* __restrict__ o0,
    ushort* __restrict__ o1, ushort* __restrict__ o2) {
    int b = blockIdx.x;
    const float* W;
    ushort* o;
    int FOUT, bb;
    if (b < 16) { W = W0; o = o0; FOUT = 128; bb = b; }
    else if (b < 32) { W = W1; o = o1; FOUT = 128; bb = b - 16; }
    else { W = W2; o = o2; FOUT = 64; bb = b - 32; }
    const int NT = FOUT / 16;
    int idx = bb * 256 + threadIdx.x;
    if (idx >= 128 * FOUT / 4) return;
    float4 v = ((const float4*)W)[idx];
    int e0 = idx * 4;
    int k = e0 / FOUT, c0 = e0 - k * FOUT;
    int kstep = k >> 5, g = (k >> 3) & 3, i = k & 7;
    float vv[4] = {v.x, v.y, v.z, v.w};
#pragma unroll
    for (int d = 0; d < 4; ++d) {
        int c = c0 + d;
        int tile = c >> 4, l16 = c & 15;
        int lane = g * 16 + l16;
        ushort hi = bf16_rne(vv[d]);
        ushort lo = bf16_rne(vv[d] - bf16_tof(hi));
        size_t base = ((((size_t)kstep * NT + tile) * 2 + 0) * 64 + lane) * 8 + i;
        o[base] = hi;
        o[base + 512] = lo;
    }
}

// ---------------- split-bf16 MFMA GEMM + fused el/er -----------------------
// Block: 4 waves; 64 nodes x FOUT. C/D: col = lane&15, row = (lane>>4)*4+j.

template <int FOUT, int H, bool HOUT, bool HIN16>
__global__ __launch_bounds__(256) void gemm_mfma(
    const void* __restrict__ hinv, const ushort* __restrict__ wsw,
    const float* __restrict__ al, const float* __restrict__ ar,
    void* __restrict__ ftout, float* __restrict__ el, float* __restrict__ er,
    int nnodes) {
    constexpr int NT = FOUT / 16;
    constexpr int WHALF = 2 * NT * 2 * 64 * 8;
    __shared__ ushort Asw[4 * 4 * 2 * 64 * 8];  // 32 KB
    __shared__ ushort Wsw[WHALF];

    const int tid = threadIdx.x;
    const int wv = tid >> 6, lane = tid & 63;
    const int nb = blockIdx.x * 64;

    // ---- stage A ----
    {
        const int nloc = tid >> 2;  // 0..63
        const int qb = tid & 3;
        const int gw = nloc >> 4, m = nloc & 15;
        const int n = nb + nloc;
        const bool v = n < nnodes;
        if constexpr (HIN16) {
            const __half* hrow = (const __half*)hinv + (size_t)(v ? n : 0) * 128;
#pragma unroll
            for (int it = 0; it < 4; ++it) {
                int k0 = (qb + it * 4) * 8;
                uint4 x = v ? *(const uint4*)&hrow[k0]
                            : make_uint4(0, 0, 0, 0);
                const __half* hp = (const __half*)&x;
                int kstep = k0 >> 5, g = (k0 >> 3) & 3;
                int laneA = g * 16 + m;
                size_t base =
                    ((((size_t)gw * 4 + kstep) * 2 + 0) * 64 + laneA) * 8;
                ushort4 uh0, uh1, ul0, ul1;
                float f;
                ushort h;
                f = __half2float(hp[0]); h = bf16_rne(f); uh0.x = h; ul0.x = bf16_rne(f - bf16_tof(h));
                f = __half2float(hp[1]); h = bf16_rne(f); uh0.y = h; ul0.y = bf16_rne(f - bf16_tof(h));
                f = __half2float(hp[2]); h = bf16_rne(f); uh0.z = h; ul0.z = bf16_rne(f - bf16_tof(h));
                f = __half2float(hp[3]); h = bf16_rne(f); uh0.w = h; ul0.w = bf16_rne(f - bf16_tof(h));
                f = __half2float(hp[4]); h = bf16_rne(f); uh1.x = h; ul1.x = bf16_rne(f - bf16_tof(h));
                f = __half2float(hp[5]); h = bf16_rne(f); uh1.y = h; ul1.y = bf16_rne(f - bf16_tof(h));
                f = __half2float(hp[6]); h = bf16_rne(f); uh1.z = h; ul1.z = bf16_rne(f - bf16_tof(h));
                f = __half2float(hp[7]); h = bf16_rne(f); uh1.w = h; ul1.w = bf16_rne(f - bf16_tof(h));
                *(ushort4*)&Asw[base] = uh0;
                *(ushort4*)&Asw[base + 4] = uh1;
                *(ushort4*)&Asw[base + 512] = ul0;
                *(ushort4*)&Asw[base + 516] = ul1;
            }
        } else {
            const float4* hrow =
                (const float4*)((const float*)hinv + (size_t)(v ? n : 0) * 128);
#pragma unroll
            for (int it = 0; it < 8; ++it) {
                int q = qb + it * 4;
                int k0 = q * 4;
                float4 x = v ? hrow[q] : make_float4(0.f, 0.f, 0.f, 0.f);
                int kstep = k0 >> 5, g = (k0 >> 3) & 3, i0 = k0 & 7;
                int laneA = g * 16 + m;
                size_t base =
                    ((((size_t)gw * 4 + kstep) * 2 + 0) * 64 + laneA) * 8 + i0;
                float xs[4] = {x.x, x.y, x.z, x.w};
                ushort4 uh, ul;
                ushort h;
                h = bf16_rne(xs[0]); uh.x = h; ul.x = bf16_rne(xs[0] - bf16_tof(h));
                h = bf16_rne(xs[1]); uh.y = h; ul.y = bf16_rne(xs[1] - bf16_tof(h));
                h = bf16_rne(xs[2]); uh.z = h; ul.z = bf16_rne(xs[2] - bf16_tof(h));
                h = bf16_rne(xs[3]); uh.w = h; ul.w = bf16_rne(xs[3] - bf16_tof(h));
                *(ushort4*)&Asw[base] = uh;
                *(ushort4*)&Asw[base + 512] = ul;
            }
        }
    }

    f32x4 acc[NT];
#pragma unroll
    for (int t = 0; t < NT; ++t) acc[t] = (f32x4){0.f, 0.f, 0.f, 0.f};

#pragma unroll
    for (int kh = 0; kh < 2; ++kh) {
        __syncthreads();
        {
            const uint4* srcp = (const uint4*)(wsw + (size_t)kh * WHALF);
            uint4* dstp = (uint4*)Wsw;
            constexpr int CNT = WHALF / 8;
#pragma unroll
            for (int ii = 0; ii < CNT / 256; ++ii)
                dstp[tid + ii * 256] = srcp[tid + ii * 256];
        }
        __syncthreads();

#pragma unroll
        for (int ks2 = 0; ks2 < 2; ++ks2) {
            const int kstep = kh * 2 + ks2;
            bf16x8 ahi = *(const bf16x8*)
                &Asw[(((wv * 4 + kstep) * 2 + 0) * 64 + lane) * 8];
            bf16x8 alo = *(const bf16x8*)
                &Asw[(((wv * 4 + kstep) * 2 + 1) * 64 + lane) * 8];
#pragma unroll
            for (int t = 0; t < NT; ++t) {
                bf16x8 bhi = *(const bf16x8*)
                    &Wsw[(((ks2 * NT + t) * 2 + 0) * 64 + lane) * 8];
                bf16x8 blo = *(const bf16x8*)
                    &Wsw[(((ks2 * NT + t) * 2 + 1) * 64 + lane) * 8];
                acc[t] = __builtin_amdgcn_mfma_f32_16x16x32_bf16(ahi, bhi, acc[t], 0, 0, 0);
                acc[t] = __builtin_amdgcn_mfma_f32_16x16x32_bf16(ahi, blo, acc[t], 0, 0, 0);
                acc[t] = __builtin_amdgcn_mfma_f32_16x16x32_bf16(alo, bhi, acc[t], 0, 0, 0);
            }
        }
    }

    // ---- epilogue ----
    const int g = lane >> 4, l16 = lane & 15;
    const int nrow0 = nb + wv * 16 + g * 4;

    if constexpr (H == 4) {
#pragma unroll
        for (int h = 0; h < 4; ++h) {
            float a0 = al[h * 32 + l16], a1 = al[h * 32 + 16 + l16];
            float r0 = ar[h * 32 + l16], r1 = ar[h * 32 + 16 + l16];
#pragma unroll
            for (int j = 0; j < 4; ++j) {
                float pl = acc[2 * h][j] * a0 + acc[2 * h + 1][j] * a1;
                float pr = acc[2 * h][j] * r0 + acc[2 * h + 1][j] * r1;
#pragma unroll
                for (int msk = 1; msk < 16; msk <<= 1) {
                    pl += __shfl_xor(pl, msk);
                    pr += __shfl_xor(pr, msk);
                }
                int n = nrow0 + j;
                if (l16 == 0 && n < nnodes) {
                    el[(size_t)n * 4 + h] = pl;
                    er[(size_t)n * 4 + h] = pr;
                }
            }
        }
    } else {
#pragma unroll
        for (int j = 0; j < 4; ++j) {
            float pl = 0.f, pr = 0.f;
#pragma unroll
            for (int t = 0; t < NT; ++t) {
                pl = fmaf(acc[t][j], al[t * 16 + l16], pl);
                pr = fmaf(acc[t][j], ar[t * 16 + l16], pr);
            }
#pragma unroll
            for (int msk = 1; msk < 16; msk <<= 1) {
                pl += __shfl_xor(pl, msk);
                pr += __shfl_xor(pr, msk);
            }
            int n = nrow0 + j;
            if (l16 == 0 && n < nnodes) {
                el[n] = pl;
                er[n] = pr;
            }
        }
    }

#pragma unroll
    for (int j = 0; j < 4; ++j) {
        int n = nrow0 + j;
        if (n < nnodes) {
            if constexpr (HOUT) {
                __half* fth = (__half*)ftout;
#pragma unroll
                for (int t = 0; t < NT; ++t)
                    fth[(size_t)n * FOUT + t * 16 + l16] =
                        __float2half_rn(acc[t][j]);
            } else {
                float* ftf = (float*)ftout;
#pragma unroll
                for (int t = 0; t < NT; ++t)
                    ftf[(size_t)n * FOUT + t * 16 + l16] = acc[t][j];
            }
        }
    }
}

// ---------------- FUSED attention-weight + gather-accumulate ---------------
// 4 nodes/wave (16 lanes each). CPL = F/16. Depth-2 pipelined 8-edge batches
// (up to 32 loads in flight per wave). Tail masked via (e0+i<end); gather
// address clamped in-bounds.

template <int F, int H, bool RELU, bool HIN, bool HOUT16>
__global__ __launch_bounds__(256) void gat_aggregate(
    const int* __restrict__ rowptr, const int* __restrict__ colx,
    const float* __restrict__ el, const float* __restrict__ er,
    const void* __restrict__ ftv, const float* __restrict__ bias,
    void* __restrict__ outv, int nnodes) {
    constexpr int CPL = F / 16;  // 8 (F=128) or 4 (F=64)
    constexpr int UN = 8;        // edges per issue batch
    const int tid = threadIdx.x, wv = tid >> 6, lane = tid & 63;
    const int grp = lane >> 4, sub = lane & 15;
    const int n = blockIdx.x * 16 + wv * 4 + grp;
    const bool valid = n < nnodes;
    const int nn = valid ? n : 0;

    const int start = rowptr[nn];
    const int end = valid ? rowptr[nn + 1] : start;
    int md = end - start;
    md = max(md, __shfl_xor(md, 16));
    md = max(md, __shfl_xor(md, 32));
    const int nit = (md + 2 * UN - 1) / (2 * UN);

    const int head = (H == 4) ? (sub >> 2) : 0;
    const float er_s = (H == 4) ? er[(size_t)nn * 4 + head] : er[nn];

    float sA = 0.f, sB = 0.f;
    float acc[CPL];
#pragma unroll
    for (int c = 0; c < CPL; ++c) acc[c] = 0.f;

    float xA[UN], xB[UN];
    uint4 hA[UN], hB[UN];

    auto issue = [&](float (&xX)[UN], uint4 (&hX)[UN], int e0) {
#pragma unroll
        for (int i = 0; i < UN; ++i) {
            int ee = e0 + i;
            int eec = max(min(ee, end - 1), 0);
            int sn = colx[eec];
            if constexpr (HIN) {
                const __half* fth = (const __half*)ftv;
                if constexpr (CPL == 8) {
                    hX[i] = *(const uint4*)&fth[(size_t)sn * F + sub * 8];
                } else {
                    uint2 t2 = *(const uint2*)&fth[(size_t)sn * F + sub * 4];
                    hX[i].x = t2.x;
                    hX[i].y = t2.y;
                }
            } else {
                const float* ftf = (const float*)ftv;
                float4 f = *(const float4*)&ftf[(size_t)sn * F + sub * 4];
                hX[i].x = __float_as_uint(f.x);
                hX[i].y = __float_as_uint(f.y);
                hX[i].z = __float_as_uint(f.z);
                hX[i].w = __float_as_uint(f.w);
            }
            xX[i] = (H == 4) ? el[(size_t)sn * 4 + head] : el[sn];
        }
    };
    auto compute = [&](float (&xX)[UN], uint4 (&hX)[UN], int e0, float& sX) {
#pragma unroll
        for (int i = 0; i < UN; ++i) {
            float x = xX[i] + er_s;
            x = fmaxf(x, 0.2f * x);  // leaky_relu
            float p = __expf(x);
            p = (e0 + i < end) ? p : 0.f;
            sX += p;
            if constexpr (HIN) {
                const __half* hv = (const __half*)&hX[i];
#pragma unroll
                for (int c = 0; c < CPL; ++c)
                    acc[c] = fmaf(p, __half2float(hv[c]), acc[c]);
            } else {
                const float* fv = (const float*)&hX[i];
#pragma unroll
                for (int c = 0; c < CPL; ++c)
                    acc[c] = fmaf(p, fv[c], acc[c]);
            }
        }
    };

    int e0 = start;
    issue(xA, hA, e0);
    for (int it = 0; it < nit; ++it) {
        issue(xB, hB, e0 + UN);            // batch k+1 in flight
        compute(xA, hA, e0, sA);           // consume batch k
        issue(xA, hA, e0 + 2 * UN);        // batch k+2 in flight
        compute(xB, hB, e0 + UN, sB);      // consume batch k+1
        e0 += 2 * UN;
    }

    if (!valid) return;
    float s = sA + sB;
    float inv = 1.0f / s;  // deg >= 1 guaranteed
    float o[CPL];
#pragma unroll
    for (int c = 0; c < CPL; ++c) {
        o[c] = acc[c] * inv + bias[sub * CPL + c];
        if (RELU) o[c] = fmaxf(o[c], 0.f);
    }
    if constexpr (HOUT16) {
        __half* oh = (__half*)outv;
        uint4 u;
        ushort* up = (ushort*)&u;
#pragma unroll
        for (int c = 0; c < CPL; ++c)
            up[c] = __half_as_ushort(__float2half_rn(o[c]));
        if constexpr (CPL == 8) {
            *(uint4*)&oh[(size_t)n * F + sub * 8] = u;
        } else {
            *(uint2*)&oh[(size_t)n * F + sub * 4] = make_uint2(u.x, u.y);
        }
    } else {
        float* of = (float*)outv;
        if constexpr (CPL == 8) {
            *(float4*)&of[(size_t)n * F + sub * 8] =
                make_float4(o[0], o[1], o[2], o[3]);
            *(float4*)&of[(size_t)n * F + sub * 8 + 4] =
                make_float4(o[4], o[5], o[6], o[7]);
        } else {
            *(float4*)&of[(size_t)n * F + sub * 4] =
                make_float4(o[0], o[1], o[2], o[3]);
        }
    }
}

// ---------------- host launch ----------------

static inline size_t alignup(size_t x) { return (x + 255) & ~(size_t)255; }

extern "C" void kernel_launch(void* const* d_in, const int* in_sizes, int n_in,
                              void* d_out, int out_size, void* d_ws, size_t ws_size,
                              hipStream_t stream) {
    const float* features = (const float*)d_in[0];
    const int* src = (const int*)d_in[1];
    const int* dst = (const int*)d_in[2];
    const float* W0 = (const float*)d_in[3];
    const float* al0 = (const float*)d_in[4];
    const float* ar0 = (const float*)d_in[5];
    const float* b0 = (const float*)d_in[6];
    const float* W1 = (const float*)d_in[7];
    const float* al1 = (const float*)d_in[8];
    const float* ar1 = (const float*)d_in[9];
    const float* b1 = (const float*)d_in[10];
    const float* W2 = (const float*)d_in[11];
    const float* al2 = (const float*)d_in[12];
    const float* ar2 = (const float*)d_in[13];
    const float* b2 = (const float*)d_in[14];
    float* out = (float*)d_out;

    const int N = in_sizes[0] / 128;  // 100000
    const int E = in_sizes[1];        // 1600000
    const int nebs = (E + EPB - 1) / EPB;   // sort blocks (391)
    const int nbuck = (N + 511) >> BSH;     // 196 buckets

    char* w = (char*)d_ws;
    int* rowptr = (int*)w;       w += alignup((size_t)(N + 1) * 4);
    int* colx = (int*)w;         w += alignup((size_t)E * 4 + 256);
    float* ft32 = (float*)w;     w += alignup((size_t)N * 64 * 4);
    __half* ft16 = (__half*)w;   w += alignup((size_t)N * 128 * 2);
    __half* hbuf16 = (__half*)w; w += alignup((size_t)N * 128 * 2);
    float* el = (float*)w;       w += alignup((size_t)N * 4 * 4);
    float* er = (float*)w;       w += alignup((size_t)N * 4 * 4);
    unsigned* ebuf = (unsigned*)w; w += alignup((size_t)E * 4);
    int* cmat = (int*)w;         w += alignup((size_t)256 * nebs * 4);
    int* rowtot = (int*)w;       w += alignup(256 * 4);
    int* bbase = (int*)w;        w += alignup(256 * 4);
    ushort* wsw0 = (ushort*)w;   w += alignup(128 * 128 * 2 * 2);
    ushort* wsw1 = (ushort*)w;   w += alignup(128 * 128 * 2 * 2);
    ushort* wsw2 = (ushort*)w;   w += alignup(128 * 64 * 2 * 2);

    // CSR build (atomic-free bucketed counting sort, u32-packed)
    ehist<<<nebs, 256, 0, stream>>>(dst, cmat, E, nebs);
    bscan<<<nbuck, 512, 0, stream>>>(cmat, rowtot, nebs);
    bbase_scan<<<1, 256, 0, stream>>>(rowtot, bbase, nbuck);
    escatter<<<nebs, 256, 0, stream>>>(src, dst, cmat, bbase, ebuf, E, nebs);
    bucket_fill<<<nbuck, 512, 0, stream>>>(ebuf, bbase, rowptr, colx, N, E, nbuck);

    // W pre-swizzle (single launch for all three weights)
    wprep_all<<<40, 256, 0, stream>>>(W0, W1, W2, wsw0, wsw1, wsw2);

    const int gG = (N + 63) / 64;
    const int gAgg = (N + 15) / 16;  // 4 nodes/wave, 4 waves/block

    // Layer 0: features(fp32) -> ft16 -> hbuf16
    gemm_mfma<128, 4, true, false><<<gG, 256, 0, stream>>>(features, wsw0, al0, ar0, ft16, el, er, N);
    gat_aggregate<128, 4, true, true, true><<<gAgg, 256, 0, stream>>>(rowptr, colx, el, er, ft16, b0, hbuf16, N);

    // Layer 1: hbuf16 -> ft16 -> hbuf16
    gemm_mfma<128, 4, true, true><<<gG, 256, 0, stream>>>(hbuf16, wsw1, al1, ar1, ft16, el, er, N);
    gat_aggregate<128, 4, true, true, true><<<gAgg, 256, 0, stream>>>(rowptr, colx, el, er, ft16, b1, hbuf16, N);

    // Layer 2: hbuf16 -> ft32 -> out (fp32)
    gemm_mfma<64, 1, false, true><<<gG, 256, 0, stream>>>(hbuf16, wsw2, al2, ar2, ft32, el, er, N);
    gat_aggregate<64, 1, false, false, false><<<gAgg, 256, 0, stream>>>(rowptr, colx, el, er, ft32, b2, out, N);
}

// Round 17
// 318.647 us; speedup vs baseline: 1.1504x; 1.1504x over previous
//
#include <hip/hip_runtime.h>
#include <hip/hip_bf16.h>
#include <hip/hip_fp16.h>
#include <math.h>

// ---------------------------------------------------------------------------
// GAT (3-layer, DGL-style) on MI355X.
// CSR build via bucketed counting sort (u32-packed, no global atomics).
// Per layer:
//   gemm_mfma: bf16 split (hi+lo) MFMA GEMM (fp32 accuracy at matrix rate).
//   gat_aggregate: fused attention-weight + gather-accumulate, 4 nodes/wave,
//                  depth-2 pipelined 4-edge batches.
// ALL ft tables fp16 (gather-traffic floor); final out fp32.
// ---------------------------------------------------------------------------

constexpr int BSH = 9;            // 512 nodes per bucket
constexpr int EPB = 4096;         // edges per sort block

typedef __attribute__((ext_vector_type(8))) short bf16x8;
typedef __attribute__((ext_vector_type(4))) float f32x4;

__device__ __forceinline__ ushort bf16_rne(float f) {
    unsigned u = __float_as_uint(f);
    u += 0x7FFF + ((u >> 16) & 1);
    return (ushort)(u >> 16);
}
__device__ __forceinline__ float bf16_tof(ushort h) {
    return __uint_as_float(((unsigned)h) << 16);
}

// ---------------- CSR build ----------------

__global__ __launch_bounds__(256) void ehist(const int* __restrict__ dst,
                                             int* __restrict__ cmat,
                                             int E, int nebs) {
    __shared__ int lh[256];
    const int t = threadIdx.x;
    lh[t] = 0;
    __syncthreads();
    const int base = blockIdx.x * EPB;
    const int cntE = min(EPB, E - base);
    for (int i = t; i < cntE; i += 256) atomicAdd(&lh[dst[base + i] >> BSH], 1);
    __syncthreads();
    cmat[t * nebs + blockIdx.x] = lh[t];  // bucket-major
}

__global__ __launch_bounds__(512) void bscan(int* __restrict__ cmat,
                                             int* __restrict__ rowtot, int nebs) {
    __shared__ int sh[512];
    const int b = blockIdx.x, t = threadIdx.x;
    int v = (t < nebs) ? cmat[b * nebs + t] : 0;
    sh[t] = v;
    __syncthreads();
    for (int off = 1; off < 512; off <<= 1) {
        int u = (t >= off) ? sh[t - off] : 0;
        __syncthreads();
        sh[t] += u;
        __syncthreads();
    }
    if (t < nebs) cmat[b * nebs + t] = sh[t] - v;
    if (t == 511) rowtot[b] = sh[511];
}

__global__ __launch_bounds__(256) void bbase_scan(const int* __restrict__ rowtot,
                                                  int* __restrict__ bbase, int nbuck) {
    __shared__ int sh[256];
    const int t = threadIdx.x;
    int v = (t < nbuck) ? rowtot[t] : 0;
    sh[t] = v;
    __syncthreads();
    for (int off = 1; off < 256; off <<= 1) {
        int u = (t >= off) ? sh[t - off] : 0;
        __syncthreads();
        sh[t] += u;
        __syncthreads();
    }
    bbase[t] = sh[t] - v;  // exclusive
}

__global__ __launch_bounds__(256) void escatter(
    const int* __restrict__ src, const int* __restrict__ dst,
    const int* __restrict__ cmat, const int* __restrict__ bbase,
    unsigned* __restrict__ ebuf, int E, int nebs) {
    __shared__ unsigned sbuf[EPB];        // 16 KB
    __shared__ unsigned char sbk[EPB];    // 4 KB
    __shared__ int lh[256], lstart[256], lcur[256], sh[256];
    const int t = threadIdx.x;
    const int base = blockIdx.x * EPB;
    const int cntE = min(EPB, E - base);

    lh[t] = 0;
    __syncthreads();
    for (int i = t; i < cntE; i += 256) atomicAdd(&lh[dst[base + i] >> BSH], 1);
    __syncthreads();
    {
        int v = lh[t];
        sh[t] = v;
        __syncthreads();
        for (int off = 1; off < 256; off <<= 1) {
            int u = (t >= off) ? sh[t - off] : 0;
            __syncthreads();
            sh[t] += u;
            __syncthreads();
        }
        lstart[t] = sh[t] - v;
        lcur[t] = sh[t] - v;
    }
    __syncthreads();
    for (int i = t; i < cntE; i += 256) {
        int d = dst[base + i], s = src[base + i];
        int bk = d >> BSH;
        int r = atomicAdd(&lcur[bk], 1);
        sbuf[r] = ((unsigned)(d & 511) << 17) | (unsigned)s;
        sbk[r] = (unsigned char)bk;
    }
    __syncthreads();
    for (int j = t; j < cntE; j += 256) {
        int bk = sbk[j];
        int gpos = bbase[bk] + cmat[bk * nebs + blockIdx.x] + (j - lstart[bk]);
        ebuf[gpos] = sbuf[j];
    }
}

__global__ __launch_bounds__(512) void bucket_fill(
    const unsigned* __restrict__ ebuf, const int* __restrict__ bbase,
    int* __restrict__ rowptr, int* __restrict__ colx, int N, int E, int nbuck) {
    __shared__ int cnt[512], nxtl[512], sh[512];
    const int b = blockIdx.x, t = threadIdx.x;
    const int nodebase = b << BSH;
    const int nn = min(512, N - nodebase);
    const int estart = bbase[b];
    const int eend = (b + 1 < 256) ? bbase[b + 1] : E;

    cnt[t] = 0;
    __syncthreads();
    for (int i = estart + t; i < eend; i += 512)
        atomicAdd(&cnt[ebuf[i] >> 17], 1);
    __syncthreads();
    int v = cnt[t];
    sh[t] = v;
    __syncthreads();
    for (int off = 1; off < 512; off <<= 1) {
        int u = (t >= off) ? sh[t - off] : 0;
        __syncthreads();
        sh[t] += u;
        __syncthreads();
    }
    if (t < nn) rowptr[nodebase + t + 1] = estart + sh[t];
    if (b == 0 && t == 0) rowptr[0] = 0;
    nxtl[t] = estart + sh[t] - v;
    __syncthreads();
    for (int i = estart + t; i < eend; i += 512) {
        unsigned v2 = ebuf[i];
        int dl = v2 >> 17;
        int pos = atomicAdd(&nxtl[dl], 1);
        colx[pos] = (int)(v2 & 0x1FFFFu);
    }
}

// ---------------- W prep (all 3 weights, one launch) ----------------
// Layout: [kstep:K/32][tile:FOUT/16][half:2][lane:64][i:8] ushort.

__global__ __launch_bounds__(256) void wprep_all(
    const float* __restrict__ W0, const float* __restrict__ W1,
    const float* __restrict__ W2, ushort* __restrict__ o0,
    ushort* __restrict__ o1, ushort* __restrict__ o2) {
    int b = blockIdx.x;
    const float* W;
    ushort* o;
    int FOUT, bb;
    if (b < 16) { W = W0; o = o0; FOUT = 128; bb = b; }
    else if (b < 32) { W = W1; o = o1; FOUT = 128; bb = b - 16; }
    else { W = W2; o = o2; FOUT = 64; bb = b - 32; }
    const int NT = FOUT / 16;
    int idx = bb * 256 + threadIdx.x;
    if (idx >= 128 * FOUT / 4) return;
    float4 v = ((const float4*)W)[idx];
    int e0 = idx * 4;
    int k = e0 / FOUT, c0 = e0 - k * FOUT;
    int kstep = k >> 5, g = (k >> 3) & 3, i = k & 7;
    float vv[4] = {v.x, v.y, v.z, v.w};
#pragma unroll
    for (int d = 0; d < 4; ++d) {
        int c = c0 + d;
        int tile = c >> 4, l16 = c & 15;
        int lane = g * 16 + l16;
        ushort hi = bf16_rne(vv[d]);
        ushort lo = bf16_rne(vv[d] - bf16_tof(hi));
        size_t base = ((((size_t)kstep * NT + tile) * 2 + 0) * 64 + lane) * 8 + i;
        o[base] = hi;
        o[base + 512] = lo;
    }
}

// ---------------- split-bf16 MFMA GEMM + fused el/er -----------------------
// Block: 4 waves; 64 nodes x FOUT. C/D: col = lane&15, row = (lane>>4)*4+j.

template <int FOUT, int H, bool HOUT, bool HIN16>
__global__ __launch_bounds__(256) void gemm_mfma(
    const void* __restrict__ hinv, const ushort* __restrict__ wsw,
    const float* __restrict__ al, const float* __restrict__ ar,
    void* __restrict__ ftout, float* __restrict__ el, float* __restrict__ er,
    int nnodes) {
    constexpr int NT = FOUT / 16;
    constexpr int WHALF = 2 * NT * 2 * 64 * 8;
    __shared__ ushort Asw[4 * 4 * 2 * 64 * 8];  // 32 KB
    __shared__ ushort Wsw[WHALF];

    const int tid = threadIdx.x;
    const int wv = tid >> 6, lane = tid & 63;
    const int nb = blockIdx.x * 64;

    // ---- stage A ----
    {
        const int nloc = tid >> 2;  // 0..63
        const int qb = tid & 3;
        const int gw = nloc >> 4, m = nloc & 15;
        const int n = nb + nloc;
        const bool v = n < nnodes;
        if constexpr (HIN16) {
            const __half* hrow = (const __half*)hinv + (size_t)(v ? n : 0) * 128;
#pragma unroll
            for (int it = 0; it < 4; ++it) {
                int k0 = (qb + it * 4) * 8;
                uint4 x = v ? *(const uint4*)&hrow[k0]
                            : make_uint4(0, 0, 0, 0);
                const __half* hp = (const __half*)&x;
                int kstep = k0 >> 5, g = (k0 >> 3) & 3;
                int laneA = g * 16 + m;
                size_t base =
                    ((((size_t)gw * 4 + kstep) * 2 + 0) * 64 + laneA) * 8;
                ushort4 uh0, uh1, ul0, ul1;
                float f;
                ushort h;
                f = __half2float(hp[0]); h = bf16_rne(f); uh0.x = h; ul0.x = bf16_rne(f - bf16_tof(h));
                f = __half2float(hp[1]); h = bf16_rne(f); uh0.y = h; ul0.y = bf16_rne(f - bf16_tof(h));
                f = __half2float(hp[2]); h = bf16_rne(f); uh0.z = h; ul0.z = bf16_rne(f - bf16_tof(h));
                f = __half2float(hp[3]); h = bf16_rne(f); uh0.w = h; ul0.w = bf16_rne(f - bf16_tof(h));
                f = __half2float(hp[4]); h = bf16_rne(f); uh1.x = h; ul1.x = bf16_rne(f - bf16_tof(h));
                f = __half2float(hp[5]); h = bf16_rne(f); uh1.y = h; ul1.y = bf16_rne(f - bf16_tof(h));
                f = __half2float(hp[6]); h = bf16_rne(f); uh1.z = h; ul1.z = bf16_rne(f - bf16_tof(h));
                f = __half2float(hp[7]); h = bf16_rne(f); uh1.w = h; ul1.w = bf16_rne(f - bf16_tof(h));
                *(ushort4*)&Asw[base] = uh0;
                *(ushort4*)&Asw[base + 4] = uh1;
                *(ushort4*)&Asw[base + 512] = ul0;
                *(ushort4*)&Asw[base + 516] = ul1;
            }
        } else {
            const float4* hrow =
                (const float4*)((const float*)hinv + (size_t)(v ? n : 0) * 128);
#pragma unroll
            for (int it = 0; it < 8; ++it) {
                int q = qb + it * 4;
                int k0 = q * 4;
                float4 x = v ? hrow[q] : make_float4(0.f, 0.f, 0.f, 0.f);
                int kstep = k0 >> 5, g = (k0 >> 3) & 3, i0 = k0 & 7;
                int laneA = g * 16 + m;
                size_t base =
                    ((((size_t)gw * 4 + kstep) * 2 + 0) * 64 + laneA) * 8 + i0;
                float xs[4] = {x.x, x.y, x.z, x.w};
                ushort4 uh, ul;
                ushort h;
                h = bf16_rne(xs[0]); uh.x = h; ul.x = bf16_rne(xs[0] - bf16_tof(h));
                h = bf16_rne(xs[1]); uh.y = h; ul.y = bf16_rne(xs[1] - bf16_tof(h));
                h = bf16_rne(xs[2]); uh.z = h; ul.z = bf16_rne(xs[2] - bf16_tof(h));
                h = bf16_rne(xs[3]); uh.w = h; ul.w = bf16_rne(xs[3] - bf16_tof(h));
                *(ushort4*)&Asw[base] = uh;
                *(ushort4*)&Asw[base + 512] = ul;
            }
        }
    }

    f32x4 acc[NT];
#pragma unroll
    for (int t = 0; t < NT; ++t) acc[t] = (f32x4){0.f, 0.f, 0.f, 0.f};

#pragma unroll
    for (int kh = 0; kh < 2; ++kh) {
        __syncthreads();
        {
            const uint4* srcp = (const uint4*)(wsw + (size_t)kh * WHALF);
            uint4* dstp = (uint4*)Wsw;
            constexpr int CNT = WHALF / 8;
#pragma unroll
            for (int ii = 0; ii < CNT / 256; ++ii)
                dstp[tid + ii * 256] = srcp[tid + ii * 256];
        }
        __syncthreads();

#pragma unroll
        for (int ks2 = 0; ks2 < 2; ++ks2) {
            const int kstep = kh * 2 + ks2;
            bf16x8 ahi = *(const bf16x8*)
                &Asw[(((wv * 4 + kstep) * 2 + 0) * 64 + lane) * 8];
            bf16x8 alo = *(const bf16x8*)
                &Asw[(((wv * 4 + kstep) * 2 + 1) * 64 + lane) * 8];
#pragma unroll
            for (int t = 0; t < NT; ++t) {
                bf16x8 bhi = *(const bf16x8*)
                    &Wsw[(((ks2 * NT + t) * 2 + 0) * 64 + lane) * 8];
                bf16x8 blo = *(const bf16x8*)
                    &Wsw[(((ks2 * NT + t) * 2 + 1) * 64 + lane) * 8];
                acc[t] = __builtin_amdgcn_mfma_f32_16x16x32_bf16(ahi, bhi, acc[t], 0, 0, 0);
                acc[t] = __builtin_amdgcn_mfma_f32_16x16x32_bf16(ahi, blo, acc[t], 0, 0, 0);
                acc[t] = __builtin_amdgcn_mfma_f32_16x16x32_bf16(alo, bhi, acc[t], 0, 0, 0);
            }
        }
    }

    // ---- epilogue ----
    const int g = lane >> 4, l16 = lane & 15;
    const int nrow0 = nb + wv * 16 + g * 4;

    if constexpr (H == 4) {
#pragma unroll
        for (int h = 0; h < 4; ++h) {
            float a0 = al[h * 32 + l16], a1 = al[h * 32 + 16 + l16];
            float r0 = ar[h * 32 + l16], r1 = ar[h * 32 + 16 + l16];
#pragma unroll
            for (int j = 0; j < 4; ++j) {
                float pl = acc[2 * h][j] * a0 + acc[2 * h + 1][j] * a1;
                float pr = acc[2 * h][j] * r0 + acc[2 * h + 1][j] * r1;
#pragma unroll
                for (int msk = 1; msk < 16; msk <<= 1) {
                    pl += __shfl_xor(pl, msk);
                    pr += __shfl_xor(pr, msk);
                }
                int n = nrow0 + j;
                if (l16 == 0 && n < nnodes) {
                    el[(size_t)n * 4 + h] = pl;
                    er[(size_t)n * 4 + h] = pr;
                }
            }
        }
    } else {
#pragma unroll
        for (int j = 0; j < 4; ++j) {
            float pl = 0.f, pr = 0.f;
#pragma unroll
            for (int t = 0; t < NT; ++t) {
                pl = fmaf(acc[t][j], al[t * 16 + l16], pl);
                pr = fmaf(acc[t][j], ar[t * 16 + l16], pr);
            }
#pragma unroll
            for (int msk = 1; msk < 16; msk <<= 1) {
                pl += __shfl_xor(pl, msk);
                pr += __shfl_xor(pr, msk);
            }
            int n = nrow0 + j;
            if (l16 == 0 && n < nnodes) {
                el[n] = pl;
                er[n] = pr;
            }
        }
    }

#pragma unroll
    for (int j = 0; j < 4; ++j) {
        int n = nrow0 + j;
        if (n < nnodes) {
            if constexpr (HOUT) {
                __half* fth = (__half*)ftout;
#pragma unroll
                for (int t = 0; t < NT; ++t)
                    fth[(size_t)n * FOUT + t * 16 + l16] =
                        __float2half_rn(acc[t][j]);
            } else {
                float* ftf = (float*)ftout;
#pragma unroll
                for (int t = 0; t < NT; ++t)
                    ftf[(size_t)n * FOUT + t * 16 + l16] = acc[t][j];
            }
        }
    }
}

// ---------------- FUSED attention-weight + gather-accumulate ---------------
// 4 nodes/wave (16 lanes each). CPL = F/16. Depth-2 pipelined 4-edge batches.
// Tail masked via (e0+i<end); gather address clamped in-bounds.

template <int F, int H, bool RELU, bool HIN, bool HOUT16>
__global__ __launch_bounds__(256) void gat_aggregate(
    const int* __restrict__ rowptr, const int* __restrict__ colx,
    const float* __restrict__ el, const float* __restrict__ er,
    const void* __restrict__ ftv, const float* __restrict__ bias,
    void* __restrict__ outv, int nnodes) {
    constexpr int CPL = F / 16;  // 8 (F=128) or 4 (F=64)
    const int tid = threadIdx.x, wv = tid >> 6, lane = tid & 63;
    const int grp = lane >> 4, sub = lane & 15;
    const int n = blockIdx.x * 16 + wv * 4 + grp;
    const bool valid = n < nnodes;
    const int nn = valid ? n : 0;

    const int start = rowptr[nn];
    const int end = valid ? rowptr[nn + 1] : start;
    int md = end - start;
    md = max(md, __shfl_xor(md, 16));
    md = max(md, __shfl_xor(md, 32));
    const int nit = (md + 7) / 8;

    const int head = (H == 4) ? (sub >> 2) : 0;
    const float er_s = (H == 4) ? er[(size_t)nn * 4 + head] : er[nn];

    float sA = 0.f, sB = 0.f;
    float acc[CPL];
#pragma unroll
    for (int c = 0; c < CPL; ++c) acc[c] = 0.f;

    float xA[4], xB[4];
    uint4 hA[4], hB[4];

    auto issue = [&](float (&xX)[4], uint4 (&hX)[4], int e0) {
#pragma unroll
        for (int i = 0; i < 4; ++i) {
            int ee = e0 + i;
            int eec = max(min(ee, end - 1), 0);
            int sn = colx[eec];
            if constexpr (HIN) {
                const __half* fth = (const __half*)ftv;
                if constexpr (CPL == 8) {
                    hX[i] = *(const uint4*)&fth[(size_t)sn * F + sub * 8];
                } else {
                    uint2 t2 = *(const uint2*)&fth[(size_t)sn * F + sub * 4];
                    hX[i].x = t2.x;
                    hX[i].y = t2.y;
                }
            } else {
                const float* ftf = (const float*)ftv;
                float4 f = *(const float4*)&ftf[(size_t)sn * F + sub * 4];
                hX[i].x = __float_as_uint(f.x);
                hX[i].y = __float_as_uint(f.y);
                hX[i].z = __float_as_uint(f.z);
                hX[i].w = __float_as_uint(f.w);
            }
            xX[i] = (H == 4) ? el[(size_t)sn * 4 + head] : el[sn];
        }
    };
    auto compute = [&](float (&xX)[4], uint4 (&hX)[4], int e0, float& sX) {
#pragma unroll
        for (int i = 0; i < 4; ++i) {
            float x = xX[i] + er_s;
            x = fmaxf(x, 0.2f * x);  // leaky_relu
            float p = __expf(x);
            p = (e0 + i < end) ? p : 0.f;
            sX += p;
            if constexpr (HIN) {
                const __half* hv = (const __half*)&hX[i];
#pragma unroll
                for (int c = 0; c < CPL; ++c)
                    acc[c] = fmaf(p, __half2float(hv[c]), acc[c]);
            } else {
                const float* fv = (const float*)&hX[i];
#pragma unroll
                for (int c = 0; c < CPL; ++c)
                    acc[c] = fmaf(p, fv[c], acc[c]);
            }
        }
    };

    int e0 = start;
    issue(xA, hA, e0);
    for (int it = 0; it < nit; ++it) {
        issue(xB, hB, e0 + 4);       // batch k+1 in flight
        compute(xA, hA, e0, sA);     // consume batch k
        issue(xA, hA, e0 + 8);       // batch k+2 in flight
        compute(xB, hB, e0 + 4, sB); // consume batch k+1
        e0 += 8;
    }

    if (!valid) return;
    float s = sA + sB;
    float inv = 1.0f / s;  // deg >= 1 guaranteed
    float o[CPL];
#pragma unroll
    for (int c = 0; c < CPL; ++c) {
        o[c] = acc[c] * inv + bias[sub * CPL + c];
        if (RELU) o[c] = fmaxf(o[c], 0.f);
    }
    if constexpr (HOUT16) {
        __half* oh = (__half*)outv;
        uint4 u;
        ushort* up = (ushort*)&u;
#pragma unroll
        for (int c = 0; c < CPL; ++c)
            up[c] = __half_as_ushort(__float2half_rn(o[c]));
        if constexpr (CPL == 8) {
            *(uint4*)&oh[(size_t)n * F + sub * 8] = u;
        } else {
            *(uint2*)&oh[(size_t)n * F + sub * 4] = make_uint2(u.x, u.y);
        }
    } else {
        float* of = (float*)outv;
        if constexpr (CPL == 8) {
            *(float4*)&of[(size_t)n * F + sub * 8] =
                make_float4(o[0], o[1], o[2], o[3]);
            *(float4*)&of[(size_t)n * F + sub * 8 + 4] =
                make_float4(o[4], o[5], o[6], o[7]);
        } else {
            *(float4*)&of[(size_t)n * F + sub * 4] =
                make_float4(o[0], o[1], o[2], o[3]);
        }
    }
}

// ---------------- host launch ----------------

static inline size_t alignup(size_t x) { return (x + 255) & ~(size_t)255; }

extern "C" void kernel_launch(void* const* d_in, const int* in_sizes, int n_in,
                              void* d_out, int out_size, void* d_ws, size_t ws_size,
                              hipStream_t stream) {
    const float* features = (const float*)d_in[0];
    const int* src = (const int*)d_in[1];
    const int* dst = (const int*)d_in[2];
    const float* W0 = (const float*)d_in[3];
    const float* al0 = (const float*)d_in[4];
    const float* ar0 = (const float*)d_in[5];
    const float* b0 = (const float*)d_in[6];
    const float* W1 = (const float*)d_in[7];
    const float* al1 = (const float*)d_in[8];
    const float* ar1 = (const float*)d_in[9];
    const float* b1 = (const float*)d_in[10];
    const float* W2 = (const float*)d_in[11];
    const float* al2 = (const float*)d_in[12];
    const float* ar2 = (const float*)d_in[13];
    const float* b2 = (const float*)d_in[14];
    float* out = (float*)d_out;

    const int N = in_sizes[0] / 128;  // 100000
    const int E = in_sizes[1];        // 1600000
    const int nebs = (E + EPB - 1) / EPB;   // sort blocks (391)
    const int nbuck = (N + 511) >> BSH;     // 196 buckets

    char* w = (char*)d_ws;
    int* rowptr = (int*)w;       w += alignup((size_t)(N + 1) * 4);
    int* colx = (int*)w;         w += alignup((size_t)E * 4 + 256);
    __half* ft16 = (__half*)w;   w += alignup((size_t)N * 128 * 2);
    __half* hbuf16 = (__half*)w; w += alignup((size_t)N * 128 * 2);
    float* el = (float*)w;       w += alignup((size_t)N * 4 * 4);
    float* er = (float*)w;       w += alignup((size_t)N * 4 * 4);
    unsigned* ebuf = (unsigned*)w; w += alignup((size_t)E * 4);
    int* cmat = (int*)w;         w += alignup((size_t)256 * nebs * 4);
    int* rowtot = (int*)w;       w += alignup(256 * 4);
    int* bbase = (int*)w;        w += alignup(256 * 4);
    ushort* wsw0 = (ushort*)w;   w += alignup(128 * 128 * 2 * 2);
    ushort* wsw1 = (ushort*)w;   w += alignup(128 * 128 * 2 * 2);
    ushort* wsw2 = (ushort*)w;   w += alignup(128 * 64 * 2 * 2);

    // CSR build (atomic-free bucketed counting sort, u32-packed)
    ehist<<<nebs, 256, 0, stream>>>(dst, cmat, E, nebs);
    bscan<<<nbuck, 512, 0, stream>>>(cmat, rowtot, nebs);
    bbase_scan<<<1, 256, 0, stream>>>(rowtot, bbase, nbuck);
    escatter<<<nebs, 256, 0, stream>>>(src, dst, cmat, bbase, ebuf, E, nebs);
    bucket_fill<<<nbuck, 512, 0, stream>>>(ebuf, bbase, rowptr, colx, N, E, nbuck);

    // W pre-swizzle (single launch for all three weights)
    wprep_all<<<40, 256, 0, stream>>>(W0, W1, W2, wsw0, wsw1, wsw2);

    const int gG = (N + 63) / 64;
    const int gAgg = (N + 15) / 16;  // 4 nodes/wave, 4 waves/block

    // Layer 0: features(fp32) -> ft16 -> hbuf16
    gemm_mfma<128, 4, true, false><<<gG, 256, 0, stream>>>(features, wsw0, al0, ar0, ft16, el, er, N);
    gat_aggregate<128, 4, true, true, true><<<gAgg, 256, 0, stream>>>(rowptr, colx, el, er, ft16, b0, hbuf16, N);

    // Layer 1: hbuf16 -> ft16 -> hbuf16
    gemm_mfma<128, 4, true, true><<<gG, 256, 0, stream>>>(hbuf16, wsw1, al1, ar1, ft16, el, er, N);
    gat_aggregate<128, 4, true, true, true><<<gAgg, 256, 0, stream>>>(rowptr, colx, el, er, ft16, b1, hbuf16, N);

    // Layer 2: hbuf16 -> ft16(64, fp16) -> out (fp32)
    gemm_mfma<64, 1, true, true><<<gG, 256, 0, stream>>>(hbuf16, wsw2, al2, ar2, ft16, el, er, N);
    gat_aggregate<64, 1, false, true, false><<<gAgg, 256, 0, stream>>>(rowptr, colx, el, er, ft16, b2, out, N);
}

// Round 18
// 317.280 us; speedup vs baseline: 1.1554x; 1.0043x over previous
//
#include <hip/hip_runtime.h>
#include <hip/hip_bf16.h>
#include <hip/hip_fp16.h>
#include <math.h>

// ---------------------------------------------------------------------------
// GAT (3-layer, DGL-style) on MI355X.
// CSR build via bucketed counting sort (u32-packed, no global atomics,
// int4-vectorized reads, bucket bases computed in-kernel).
// Per layer:
//   gemm_mfma: bf16 split (hi+lo) MFMA GEMM (fp32 accuracy at matrix rate).
//   gat_aggregate: fused attention-weight + gather-accumulate, 4 nodes/wave,
//                  depth-2 pipelined 4-edge batches.
// ALL ft tables fp16 (gather-traffic floor); final out fp32.
// ---------------------------------------------------------------------------

constexpr int BSH = 9;            // 512 nodes per bucket
constexpr int EPB = 4096;         // edges per sort block

typedef __attribute__((ext_vector_type(8))) short bf16x8;
typedef __attribute__((ext_vector_type(4))) float f32x4;

__device__ __forceinline__ ushort bf16_rne(float f) {
    unsigned u = __float_as_uint(f);
    u += 0x7FFF + ((u >> 16) & 1);
    return (ushort)(u >> 16);
}
__device__ __forceinline__ float bf16_tof(ushort h) {
    return __uint_as_float(((unsigned)h) << 16);
}

// ---------------- CSR build ----------------

__global__ __launch_bounds__(256) void ehist(const int* __restrict__ dst,
                                             int* __restrict__ cmat,
                                             int E, int nebs) {
    __shared__ int lh[256];
    const int t = threadIdx.x;
    lh[t] = 0;
    __syncthreads();
    const int base = blockIdx.x * EPB;
    const int cntE = min(EPB, E - base);
    const int4* d4 = (const int4*)(dst + base);
    const int n4 = cntE >> 2;
    for (int i = t; i < n4; i += 256) {
        int4 v = d4[i];
        atomicAdd(&lh[v.x >> BSH], 1);
        atomicAdd(&lh[v.y >> BSH], 1);
        atomicAdd(&lh[v.z >> BSH], 1);
        atomicAdd(&lh[v.w >> BSH], 1);
    }
    for (int i = (n4 << 2) + t; i < cntE; i += 256)
        atomicAdd(&lh[dst[base + i] >> BSH], 1);
    __syncthreads();
    cmat[t * nebs + blockIdx.x] = lh[t];  // bucket-major
}

__global__ __launch_bounds__(512) void bscan(int* __restrict__ cmat,
                                             int* __restrict__ rowtot, int nebs) {
    __shared__ int sh[512];
    const int b = blockIdx.x, t = threadIdx.x;
    int v = (t < nebs) ? cmat[b * nebs + t] : 0;
    sh[t] = v;
    __syncthreads();
    for (int off = 1; off < 512; off <<= 1) {
        int u = (t >= off) ? sh[t - off] : 0;
        __syncthreads();
        sh[t] += u;
        __syncthreads();
    }
    if (t < nebs) cmat[b * nebs + t] = sh[t] - v;
    if (t == 511) rowtot[b] = sh[511];
}

__global__ __launch_bounds__(256) void escatter(
    const int* __restrict__ src, const int* __restrict__ dst,
    const int* __restrict__ cmat, const int* __restrict__ rowtot,
    unsigned* __restrict__ ebuf, int E, int nebs, int nbuck) {
    __shared__ unsigned sbuf[EPB];        // 16 KB
    __shared__ unsigned char sbk[EPB];    // 4 KB
    __shared__ int lh[256], lstart[256], lcur[256], sh[256], bb[256];
    const int t = threadIdx.x;
    const int base = blockIdx.x * EPB;
    const int cntE = min(EPB, E - base);

    // bucket bases from rowtot (exclusive scan)
    {
        int v = (t < nbuck) ? rowtot[t] : 0;
        sh[t] = v;
        __syncthreads();
        for (int off = 1; off < 256; off <<= 1) {
            int u = (t >= off) ? sh[t - off] : 0;
            __syncthreads();
            sh[t] += u;
            __syncthreads();
        }
        bb[t] = sh[t] - v;
    }
    lh[t] = 0;
    __syncthreads();
    {
        const int4* d4 = (const int4*)(dst + base);
        const int n4 = cntE >> 2;
        for (int i = t; i < n4; i += 256) {
            int4 v = d4[i];
            atomicAdd(&lh[v.x >> BSH], 1);
            atomicAdd(&lh[v.y >> BSH], 1);
            atomicAdd(&lh[v.z >> BSH], 1);
            atomicAdd(&lh[v.w >> BSH], 1);
        }
        for (int i = (n4 << 2) + t; i < cntE; i += 256)
            atomicAdd(&lh[dst[base + i] >> BSH], 1);
    }
    __syncthreads();
    {
        int v = lh[t];
        sh[t] = v;
        __syncthreads();
        for (int off = 1; off < 256; off <<= 1) {
            int u = (t >= off) ? sh[t - off] : 0;
            __syncthreads();
            sh[t] += u;
            __syncthreads();
        }
        lstart[t] = sh[t] - v;
        lcur[t] = sh[t] - v;
    }
    __syncthreads();
    {
        const int4* d4 = (const int4*)(dst + base);
        const int4* s4 = (const int4*)(src + base);
        const int n4 = cntE >> 2;
        for (int i = t; i < n4; i += 256) {
            int4 d = d4[i];
            int4 s = s4[i];
            int dd[4] = {d.x, d.y, d.z, d.w};
            int ss[4] = {s.x, s.y, s.z, s.w};
#pragma unroll
            for (int q = 0; q < 4; ++q) {
                int bk = dd[q] >> BSH;
                int r = atomicAdd(&lcur[bk], 1);
                sbuf[r] = ((unsigned)(dd[q] & 511) << 17) | (unsigned)ss[q];
                sbk[r] = (unsigned char)bk;
            }
        }
        for (int i = (n4 << 2) + t; i < cntE; i += 256) {
            int d = dst[base + i], s = src[base + i];
            int bk = d >> BSH;
            int r = atomicAdd(&lcur[bk], 1);
            sbuf[r] = ((unsigned)(d & 511) << 17) | (unsigned)s;
            sbk[r] = (unsigned char)bk;
        }
    }
    __syncthreads();
    for (int j = t; j < cntE; j += 256) {
        int bk = sbk[j];
        int gpos = bb[bk] + cmat[bk * nebs + blockIdx.x] + (j - lstart[bk]);
        ebuf[gpos] = sbuf[j];
    }
}

__global__ __launch_bounds__(512) void bucket_fill(
    const unsigned* __restrict__ ebuf, const int* __restrict__ rowtot,
    int* __restrict__ rowptr, int* __restrict__ colx, int N, int E, int nbuck) {
    __shared__ int cnt[512], nxtl[512], sh[512], bb[257];
    const int b = blockIdx.x, t = threadIdx.x;
    const int nodebase = b << BSH;
    const int nn = min(512, N - nodebase);

    // bucket base via exclusive scan of rowtot (first 256 threads)
    if (t < 256) {
        int v = (t < nbuck) ? rowtot[t] : 0;
        sh[t] = v;
    }
    __syncthreads();
    for (int off = 1; off < 256; off <<= 1) {
        int u = (t < 256 && t >= off) ? sh[t - off] : 0;
        __syncthreads();
        if (t < 256) sh[t] += u;
        __syncthreads();
    }
    if (t < 256) bb[t] = sh[t] - ((t < nbuck) ? rowtot[t] : 0);
    __syncthreads();
    const int estart = bb[b];
    const int eend = estart + rowtot[b];

    cnt[t] = 0;
    __syncthreads();
    for (int i = estart + t; i < eend; i += 512)
        atomicAdd(&cnt[ebuf[i] >> 17], 1);
    __syncthreads();
    int v = cnt[t];
    sh[t] = v;
    __syncthreads();
    for (int off = 1; off < 512; off <<= 1) {
        int u = (t >= off) ? sh[t - off] : 0;
        __syncthreads();
        sh[t] += u;
        __syncthreads();
    }
    if (t < nn) rowptr[nodebase + t + 1] = estart + sh[t];
    if (b == 0 && t == 0) rowptr[0] = 0;
    nxtl[t] = estart + sh[t] - v;
    __syncthreads();
    for (int i = estart + t; i < eend; i += 512) {
        unsigned v2 = ebuf[i];
        int dl = v2 >> 17;
        int pos = atomicAdd(&nxtl[dl], 1);
        colx[pos] = (int)(v2 & 0x1FFFFu);
    }
}

// ---------------- W prep (all 3 weights, one launch) ----------------
// Layout: [kstep:K/32][tile:FOUT/16][half:2][lane:64][i:8] ushort.

__global__ __launch_bounds__(256) void wprep_all(
    const float* __restrict__ W0, const float* __restrict__ W1,
    const float* __restrict__ W2, ushort* __restrict__ o0,
    ushort* __restrict__ o1, ushort* __restrict__ o2) {
    int b = blockIdx.x;
    const float* W;
    ushort* o;
    int FOUT, bb;
    if (b < 16) { W = W0; o = o0; FOUT = 128; bb = b; }
    else if (b < 32) { W = W1; o = o1; FOUT = 128; bb = b - 16; }
    else { W = W2; o = o2; FOUT = 64; bb = b - 32; }
    const int NT = FOUT / 16;
    int idx = bb * 256 + threadIdx.x;
    if (idx >= 128 * FOUT / 4) return;
    float4 v = ((const float4*)W)[idx];
    int e0 = idx * 4;
    int k = e0 / FOUT, c0 = e0 - k * FOUT;
    int kstep = k >> 5, g = (k >> 3) & 3, i = k & 7;
    float vv[4] = {v.x, v.y, v.z, v.w};
#pragma unroll
    for (int d = 0; d < 4; ++d) {
        int c = c0 + d;
        int tile = c >> 4, l16 = c & 15;
        int lane = g * 16 + l16;
        ushort hi = bf16_rne(vv[d]);
        ushort lo = bf16_rne(vv[d] - bf16_tof(hi));
        size_t base = ((((size_t)kstep * NT + tile) * 2 + 0) * 64 + lane) * 8 + i;
        o[base] = hi;
        o[base + 512] = lo;
    }
}

// ---------------- split-bf16 MFMA GEMM + fused el/er -----------------------
// Block: 4 waves; 64 nodes x FOUT. C/D: col = lane&15, row = (lane>>4)*4+j.

template <int FOUT, int H, bool HOUT, bool HIN16>
__global__ __launch_bounds__(256) void gemm_mfma(
    const void* __restrict__ hinv, const ushort* __restrict__ wsw,
    const float* __restrict__ al, const float* __restrict__ ar,
    void* __restrict__ ftout, float* __restrict__ el, float* __restrict__ er,
    int nnodes) {
    constexpr int NT = FOUT / 16;
    constexpr int WHALF = 2 * NT * 2 * 64 * 8;
    __shared__ ushort Asw[4 * 4 * 2 * 64 * 8];  // 32 KB
    __shared__ ushort Wsw[WHALF];

    const int tid = threadIdx.x;
    const int wv = tid >> 6, lane = tid & 63;
    const int nb = blockIdx.x * 64;

    // ---- stage A ----
    {
        const int nloc = tid >> 2;  // 0..63
        const int qb = tid & 3;
        const int gw = nloc >> 4, m = nloc & 15;
        const int n = nb + nloc;
        const bool v = n < nnodes;
        if constexpr (HIN16) {
            const __half* hrow = (const __half*)hinv + (size_t)(v ? n : 0) * 128;
#pragma unroll
            for (int it = 0; it < 4; ++it) {
                int k0 = (qb + it * 4) * 8;
                uint4 x = v ? *(const uint4*)&hrow[k0]
                            : make_uint4(0, 0, 0, 0);
                const __half* hp = (const __half*)&x;
                int kstep = k0 >> 5, g = (k0 >> 3) & 3;
                int laneA = g * 16 + m;
                size_t base =
                    ((((size_t)gw * 4 + kstep) * 2 + 0) * 64 + laneA) * 8;
                ushort4 uh0, uh1, ul0, ul1;
                float f;
                ushort h;
                f = __half2float(hp[0]); h = bf16_rne(f); uh0.x = h; ul0.x = bf16_rne(f - bf16_tof(h));
                f = __half2float(hp[1]); h = bf16_rne(f); uh0.y = h; ul0.y = bf16_rne(f - bf16_tof(h));
                f = __half2float(hp[2]); h = bf16_rne(f); uh0.z = h; ul0.z = bf16_rne(f - bf16_tof(h));
                f = __half2float(hp[3]); h = bf16_rne(f); uh0.w = h; ul0.w = bf16_rne(f - bf16_tof(h));
                f = __half2float(hp[4]); h = bf16_rne(f); uh1.x = h; ul1.x = bf16_rne(f - bf16_tof(h));
                f = __half2float(hp[5]); h = bf16_rne(f); uh1.y = h; ul1.y = bf16_rne(f - bf16_tof(h));
                f = __half2float(hp[6]); h = bf16_rne(f); uh1.z = h; ul1.z = bf16_rne(f - bf16_tof(h));
                f = __half2float(hp[7]); h = bf16_rne(f); uh1.w = h; ul1.w = bf16_rne(f - bf16_tof(h));
                *(ushort4*)&Asw[base] = uh0;
                *(ushort4*)&Asw[base + 4] = uh1;
                *(ushort4*)&Asw[base + 512] = ul0;
                *(ushort4*)&Asw[base + 516] = ul1;
            }
        } else {
            const float4* hrow =
                (const float4*)((const float*)hinv + (size_t)(v ? n : 0) * 128);
#pragma unroll
            for (int it = 0; it < 8; ++it) {
                int q = qb + it * 4;
                int k0 = q * 4;
                float4 x = v ? hrow[q] : make_float4(0.f, 0.f, 0.f, 0.f);
                int kstep = k0 >> 5, g = (k0 >> 3) & 3, i0 = k0 & 7;
                int laneA = g * 16 + m;
                size_t base =
                    ((((size_t)gw * 4 + kstep) * 2 + 0) * 64 + laneA) * 8 + i0;
                float xs[4] = {x.x, x.y, x.z, x.w};
                ushort4 uh, ul;
                ushort h;
                h = bf16_rne(xs[0]); uh.x = h; ul.x = bf16_rne(xs[0] - bf16_tof(h));
                h = bf16_rne(xs[1]); uh.y = h; ul.y = bf16_rne(xs[1] - bf16_tof(h));
                h = bf16_rne(xs[2]); uh.z = h; ul.z = bf16_rne(xs[2] - bf16_tof(h));
                h = bf16_rne(xs[3]); uh.w = h; ul.w = bf16_rne(xs[3] - bf16_tof(h));
                *(ushort4*)&Asw[base] = uh;
                *(ushort4*)&Asw[base + 512] = ul;
            }
        }
    }

    f32x4 acc[NT];
#pragma unroll
    for (int t = 0; t < NT; ++t) acc[t] = (f32x4){0.f, 0.f, 0.f, 0.f};

#pragma unroll
    for (int kh = 0; kh < 2; ++kh) {
        __syncthreads();
        {
            const uint4* srcp = (const uint4*)(wsw + (size_t)kh * WHALF);
            uint4* dstp = (uint4*)Wsw;
            constexpr int CNT = WHALF / 8;
#pragma unroll
            for (int ii = 0; ii < CNT / 256; ++ii)
                dstp[tid + ii * 256] = srcp[tid + ii * 256];
        }
        __syncthreads();

#pragma unroll
        for (int ks2 = 0; ks2 < 2; ++ks2) {
            const int kstep = kh * 2 + ks2;
            bf16x8 ahi = *(const bf16x8*)
                &Asw[(((wv * 4 + kstep) * 2 + 0) * 64 + lane) * 8];
            bf16x8 alo = *(const bf16x8*)
                &Asw[(((wv * 4 + kstep) * 2 + 1) * 64 + lane) * 8];
#pragma unroll
            for (int t = 0; t < NT; ++t) {
                bf16x8 bhi = *(const bf16x8*)
                    &Wsw[(((ks2 * NT + t) * 2 + 0) * 64 + lane) * 8];
                bf16x8 blo = *(const bf16x8*)
                    &Wsw[(((ks2 * NT + t) * 2 + 1) * 64 + lane) * 8];
                acc[t] = __builtin_amdgcn_mfma_f32_16x16x32_bf16(ahi, bhi, acc[t], 0, 0, 0);
                acc[t] = __builtin_amdgcn_mfma_f32_16x16x32_bf16(ahi, blo, acc[t], 0, 0, 0);
                acc[t] = __builtin_amdgcn_mfma_f32_16x16x32_bf16(alo, bhi, acc[t], 0, 0, 0);
            }
        }
    }

    // ---- epilogue ----
    const int g = lane >> 4, l16 = lane & 15;
    const int nrow0 = nb + wv * 16 + g * 4;

    if constexpr (H == 4) {
#pragma unroll
        for (int h = 0; h < 4; ++h) {
            float a0 = al[h * 32 + l16], a1 = al[h * 32 + 16 + l16];
            float r0 = ar[h * 32 + l16], r1 = ar[h * 32 + 16 + l16];
#pragma unroll
            for (int j = 0; j < 4; ++j) {
                float pl = acc[2 * h][j] * a0 + acc[2 * h + 1][j] * a1;
                float pr = acc[2 * h][j] * r0 + acc[2 * h + 1][j] * r1;
#pragma unroll
                for (int msk = 1; msk < 16; msk <<= 1) {
                    pl += __shfl_xor(pl, msk);
                    pr += __shfl_xor(pr, msk);
                }
                int n = nrow0 + j;
                if (l16 == 0 && n < nnodes) {
                    el[(size_t)n * 4 + h] = pl;
                    er[(size_t)n * 4 + h] = pr;
                }
            }
        }
    } else {
#pragma unroll
        for (int j = 0; j < 4; ++j) {
            float pl = 0.f, pr = 0.f;
#pragma unroll
            for (int t = 0; t < NT; ++t) {
                pl = fmaf(acc[t][j], al[t * 16 + l16], pl);
                pr = fmaf(acc[t][j], ar[t * 16 + l16], pr);
            }
#pragma unroll
            for (int msk = 1; msk < 16; msk <<= 1) {
                pl += __shfl_xor(pl, msk);
                pr += __shfl_xor(pr, msk);
            }
            int n = nrow0 + j;
            if (l16 == 0 && n < nnodes) {
                el[n] = pl;
                er[n] = pr;
            }
        }
    }

#pragma unroll
    for (int j = 0; j < 4; ++j) {
        int n = nrow0 + j;
        if (n < nnodes) {
            if constexpr (HOUT) {
                __half* fth = (__half*)ftout;
#pragma unroll
                for (int t = 0; t < NT; ++t)
                    fth[(size_t)n * FOUT + t * 16 + l16] =
                        __float2half_rn(acc[t][j]);
            } else {
                float* ftf = (float*)ftout;
#pragma unroll
                for (int t = 0; t < NT; ++t)
                    ftf[(size_t)n * FOUT + t * 16 + l16] = acc[t][j];
            }
        }
    }
}

// ---------------- FUSED attention-weight + gather-accumulate ---------------
// 4 nodes/wave (16 lanes each). CPL = F/16. Depth-2 pipelined 4-edge batches.
// Tail masked via (e0+i<end); gather address clamped in-bounds.

template <int F, int H, bool RELU, bool HIN, bool HOUT16>
__global__ __launch_bounds__(256) void gat_aggregate(
    const int* __restrict__ rowptr, const int* __restrict__ colx,
    const float* __restrict__ el, const float* __restrict__ er,
    const void* __restrict__ ftv, const float* __restrict__ bias,
    void* __restrict__ outv, int nnodes) {
    constexpr int CPL = F / 16;  // 8 (F=128) or 4 (F=64)
    const int tid = threadIdx.x, wv = tid >> 6, lane = tid & 63;
    const int grp = lane >> 4, sub = lane & 15;
    const int n = blockIdx.x * 16 + wv * 4 + grp;
    const bool valid = n < nnodes;
    const int nn = valid ? n : 0;

    const int start = rowptr[nn];
    const int end = valid ? rowptr[nn + 1] : start;
    int md = end - start;
    md = max(md, __shfl_xor(md, 16));
    md = max(md, __shfl_xor(md, 32));
    const int nit = (md + 7) / 8;

    const int head = (H == 4) ? (sub >> 2) : 0;
    const float er_s = (H == 4) ? er[(size_t)nn * 4 + head] : er[nn];

    float sA = 0.f, sB = 0.f;
    float acc[CPL];
#pragma unroll
    for (int c = 0; c < CPL; ++c) acc[c] = 0.f;

    float xA[4], xB[4];
    uint4 hA[4], hB[4];

    auto issue = [&](float (&xX)[4], uint4 (&hX)[4], int e0) {
#pragma unroll
        for (int i = 0; i < 4; ++i) {
            int ee = e0 + i;
            int eec = max(min(ee, end - 1), 0);
            int sn = colx[eec];
            if constexpr (HIN) {
                const __half* fth = (const __half*)ftv;
                if constexpr (CPL == 8) {
                    hX[i] = *(const uint4*)&fth[(size_t)sn * F + sub * 8];
                } else {
                    uint2 t2 = *(const uint2*)&fth[(size_t)sn * F + sub * 4];
                    hX[i].x = t2.x;
                    hX[i].y = t2.y;
                }
            } else {
                const float* ftf = (const float*)ftv;
                float4 f = *(const float4*)&ftf[(size_t)sn * F + sub * 4];
                hX[i].x = __float_as_uint(f.x);
                hX[i].y = __float_as_uint(f.y);
                hX[i].z = __float_as_uint(f.z);
                hX[i].w = __float_as_uint(f.w);
            }
            xX[i] = (H == 4) ? el[(size_t)sn * 4 + head] : el[sn];
        }
    };
    auto compute = [&](float (&xX)[4], uint4 (&hX)[4], int e0, float& sX) {
#pragma unroll
        for (int i = 0; i < 4; ++i) {
            float x = xX[i] + er_s;
            x = fmaxf(x, 0.2f * x);  // leaky_relu
            float p = __expf(x);
            p = (e0 + i < end) ? p : 0.f;
            sX += p;
            if constexpr (HIN) {
                const __half* hv = (const __half*)&hX[i];
#pragma unroll
                for (int c = 0; c < CPL; ++c)
                    acc[c] = fmaf(p, __half2float(hv[c]), acc[c]);
            } else {
                const float* fv = (const float*)&hX[i];
#pragma unroll
                for (int c = 0; c < CPL; ++c)
                    acc[c] = fmaf(p, fv[c], acc[c]);
            }
        }
    };

    int e0 = start;
    issue(xA, hA, e0);
    for (int it = 0; it < nit; ++it) {
        issue(xB, hB, e0 + 4);       // batch k+1 in flight
        compute(xA, hA, e0, sA);     // consume batch k
        issue(xA, hA, e0 + 8);       // batch k+2 in flight
        compute(xB, hB, e0 + 4, sB); // consume batch k+1
        e0 += 8;
    }

    if (!valid) return;
    float s = sA + sB;
    float inv = 1.0f / s;  // deg >= 1 guaranteed
    float o[CPL];
#pragma unroll
    for (int c = 0; c < CPL; ++c) {
        o[c] = acc[c] * inv + bias[sub * CPL + c];
        if (RELU) o[c] = fmaxf(o[c], 0.f);
    }
    if constexpr (HOUT16) {
        __half* oh = (__half*)outv;
        uint4 u;
        ushort* up = (ushort*)&u;
#pragma unroll
        for (int c = 0; c < CPL; ++c)
            up[c] = __half_as_ushort(__float2half_rn(o[c]));
        if constexpr (CPL == 8) {
            *(uint4*)&oh[(size_t)n * F + sub * 8] = u;
        } else {
            *(uint2*)&oh[(size_t)n * F + sub * 4] = make_uint2(u.x, u.y);
        }
    } else {
        float* of = (float*)outv;
        if constexpr (CPL == 8) {
            *(float4*)&of[(size_t)n * F + sub * 8] =
                make_float4(o[0], o[1], o[2], o[3]);
            *(float4*)&of[(size_t)n * F + sub * 8 + 4] =
                make_float4(o[4], o[5], o[6], o[7]);
        } else {
            *(float4*)&of[(size_t)n * F + sub * 4] =
                make_float4(o[0], o[1], o[2], o[3]);
        }
    }
}

// ---------------- host launch ----------------

static inline size_t alignup(size_t x) { return (x + 255) & ~(size_t)255; }

extern "C" void kernel_launch(void* const* d_in, const int* in_sizes, int n_in,
                              void* d_out, int out_size, void* d_ws, size_t ws_size,
                              hipStream_t stream) {
    const float* features = (const float*)d_in[0];
    const int* src = (const int*)d_in[1];
    const int* dst = (const int*)d_in[2];
    const float* W0 = (const float*)d_in[3];
    const float* al0 = (const float*)d_in[4];
    const float* ar0 = (const float*)d_in[5];
    const float* b0 = (const float*)d_in[6];
    const float* W1 = (const float*)d_in[7];
    const float* al1 = (const float*)d_in[8];
    const float* ar1 = (const float*)d_in[9];
    const float* b1 = (const float*)d_in[10];
    const float* W2 = (const float*)d_in[11];
    const float* al2 = (const float*)d_in[12];
    const float* ar2 = (const float*)d_in[13];
    const float* b2 = (const float*)d_in[14];
    float* out = (float*)d_out;

    const int N = in_sizes[0] / 128;  // 100000
    const int E = in_sizes[1];        // 1600000
    const int nebs = (E + EPB - 1) / EPB;   // sort blocks (391)
    const int nbuck = (N + 511) >> BSH;     // 196 buckets

    char* w = (char*)d_ws;
    int* rowptr = (int*)w;       w += alignup((size_t)(N + 1) * 4);
    int* colx = (int*)w;         w += alignup((size_t)E * 4 + 256);
    __half* ft16 = (__half*)w;   w += alignup((size_t)N * 128 * 2);
    __half* hbuf16 = (__half*)w; w += alignup((size_t)N * 128 * 2);
    float* el = (float*)w;       w += alignup((size_t)N * 4 * 4);
    float* er = (float*)w;       w += alignup((size_t)N * 4 * 4);
    unsigned* ebuf = (unsigned*)w; w += alignup((size_t)E * 4);
    int* cmat = (int*)w;         w += alignup((size_t)256 * nebs * 4);
    int* rowtot = (int*)w;       w += alignup(256 * 4);
    ushort* wsw0 = (ushort*)w;   w += alignup(128 * 128 * 2 * 2);
    ushort* wsw1 = (ushort*)w;   w += alignup(128 * 128 * 2 * 2);
    ushort* wsw2 = (ushort*)w;   w += alignup(128 * 64 * 2 * 2);

    // CSR build (atomic-free bucketed counting sort, u32-packed)
    ehist<<<nebs, 256, 0, stream>>>(dst, cmat, E, nebs);
    bscan<<<nbuck, 512, 0, stream>>>(cmat, rowtot, nebs);
    escatter<<<nebs, 256, 0, stream>>>(src, dst, cmat, rowtot, ebuf, E, nebs, nbuck);
    bucket_fill<<<nbuck, 512, 0, stream>>>(ebuf, rowtot, rowptr, colx, N, E, nbuck);

    // W pre-swizzle (single launch for all three weights)
    wprep_all<<<40, 256, 0, stream>>>(W0, W1, W2, wsw0, wsw1, wsw2);

    const int gG = (N + 63) / 64;
    const int gAgg = (N + 15) / 16;  // 4 nodes/wave, 4 waves/block

    // Layer 0: features(fp32) -> ft16 -> hbuf16
    gemm_mfma<128, 4, true, false><<<gG, 256, 0, stream>>>(features, wsw0, al0, ar0, ft16, el, er, N);
    gat_aggregate<128, 4, true, true, true><<<gAgg, 256, 0, stream>>>(rowptr, colx, el, er, ft16, b0, hbuf16, N);

    // Layer 1: hbuf16 -> ft16 -> hbuf16
    gemm_mfma<128, 4, true, true><<<gG, 256, 0, stream>>>(hbuf16, wsw1, al1, ar1, ft16, el, er, N);
    gat_aggregate<128, 4, true, true, true><<<gAgg, 256, 0, stream>>>(rowptr, colx, el, er, ft16, b1, hbuf16, N);

    // Layer 2: hbuf16 -> ft16(64, fp16) -> out (fp32)
    gemm_mfma<64, 1, true, true><<<gG, 256, 0, stream>>>(hbuf16, wsw2, al2, ar2, ft16, el, er, N);
    gat_aggregate<64, 1, false, true, false><<<gAgg, 256, 0, stream>>>(rowptr, colx, el, er, ft16, b2, out, N);
}